// Round 12
// baseline (101.690 us; speedup 1.0000x reference)
//
#include <hip/hip_runtime.h>

typedef unsigned int u32;
typedef unsigned short u16;

#define B_   2
#define CIN  256
#define COUT 256
#define PD   34
#define PLANE (PD*PD)        // 1156
#define P3   (PD*PD*PD)      // 39304
#define SPAT 32768           // 32*32*32

// xt2: [b][kg(32)][p(P3)][8]  (granule = 8 cin = 16B)
#define XT_BYTES ((size_t)B_ * 32 * P3 * 8 * 2)
#define WB_OFF_BYTES XT_BYTES

typedef __attribute__((ext_vector_type(8)))  short bf16x8;
typedef __attribute__((ext_vector_type(8)))  u16   u16x8;
typedef __attribute__((ext_vector_type(16))) float f32x16;

__device__ __forceinline__ u16 f2bf(float f) {
  union { float f; u32 u; } v; v.f = f;
  u32 r = v.u + 0x7FFFu + ((v.u >> 16) & 1u);   // RNE
  return (u16)(r >> 16);
}

__device__ __forceinline__ void gload_lds16(const void* g, void* l) {
  __builtin_amdgcn_global_load_lds(
      (const __attribute__((address_space(1))) u32*)g,
      (__attribute__((address_space(3))) u32*)l,
      16, 0, 0);
}

__device__ __forceinline__ int tapOff(u32 d) {
  return (d == 1) ? -PLANE : (d == 2) ? PLANE
       : (d == 3) ? -PD    : (d == 4) ? PD
       : (d == 5) ? -1     : (d == 6) ? 1 : 0;
}

// ---------------- zero only the pad border of xt2 ---------------------------
__global__ void zero_border(u16* __restrict__ xt) {
  u32 idx = blockIdx.x * 256u + threadIdx.x;   // 64 * P3 granules
  if (idx >= 64u * (u32)P3) return;
  u32 bk = idx & 63u;                          // b*32 + kg
  u32 p  = idx >> 6;
  u32 t = p / PLANE, rem = p - t * PLANE, r = rem / PD, c = rem - r * PD;
  if (!((t == 0) | (t == 33) | (r == 0) | (r == 33) | (c == 0) | (c == 33)))
    return;
  *(u16x8*)(xt + ((size_t)bk * P3 + p) * 8) = (u16x8)0;
}

// ---------------- W fp32 -> bf16, wb2[d][kg][o][8] ---------------------------
__global__ void convert_w(const float* __restrict__ W, u16* __restrict__ wb) {
  u32 idx = blockIdx.x * 256u + threadIdx.x;   // 7*32*256 = 57344
  u32 o = idx & 255u, kgd = idx >> 8;          // kgd = d*32 + kg
  u32 kg = kgd & 31u, d = kgd >> 5;
  const float* src = W + (size_t)(d * 256u + o) * CIN + kg * 8u;
  float4 f0 = ((const float4*)src)[0];
  float4 f1 = ((const float4*)src)[1];
  u16x8 v;
  v[0] = f2bf(f0.x); v[1] = f2bf(f0.y); v[2] = f2bf(f0.z); v[3] = f2bf(f0.w);
  v[4] = f2bf(f1.x); v[5] = f2bf(f1.y); v[6] = f2bf(f1.z); v[7] = f2bf(f1.w);
  *(u16x8*)(wb + (size_t)idx * 8) = v;
}

// ------- x (b,i,t,r,c) fp32 -> xt2[b][kg][p][8], COALESCED ------------------
__global__ void transpose_pad(const float* __restrict__ x, u16* __restrict__ xt) {
  u32 wg = blockIdx.x;                 // 1024 = b(2) x t(32) x rq(4) x ih(4)
  u32 ih = wg & 3u, rq = (wg >> 2) & 3u, t = (wg >> 4) & 31u, b = wg >> 9;
  u32 tid = threadIdx.x;
  u32 r = tid >> 5, c = tid & 31u, rr = rq * 8u + r;
  u32 sOff = t * 1024u + rr * 32u + c;
  u32 p = ((t + 1) * PD + (rr + 1)) * PD + 1 + c;
#pragma unroll 1
  for (u32 g = 0; g < 8; ++g) {
    u32 ig = ih * 8u + g;
    u16x8 v;
#pragma unroll
    for (int j = 0; j < 8; ++j)
      v[j] = f2bf(x[(size_t)(b * 256u + ig * 8u + (u32)j) * SPAT + sOff]);
    *(u16x8*)(xt + ((size_t)(b * 32u + ig) * P3 + p) * 8) = v;
  }
}

// ---------------- main: 4-wave 256x128 tile, BK=32, 2 blocks/CU -------------
// grid 512 = 2 blocks/CU, each SIMD holds 1 wave from EACH block -> when one
// block stalls on barrier/lgkmcnt, the other's MFMAs issue (m114 overlap).
// N-split (spatial), so only the tiny L2-hot A (weights) fetch is duplicated.
// Per wave per step: 6 gload_lds (stage T+1, issued first), 12 ds_read_b128,
// 16 MFMA 32x32x16, one __syncthreads.
__global__ __launch_bounds__(256, 2)
void conv_main(const u16* __restrict__ xt, const u16* __restrict__ wb,
               float* __restrict__ out) {
  __shared__ __align__(16) u16 ldsA[2][4][256][8];   // 32 KiB (buf, kb, cout, 8)
  __shared__ __align__(16) u16 ldsB[2][4][128][8];   // 16 KiB (buf, kb, n, 8)

  u32 bid = blockIdx.x;
  u32 id2 = (bid & 7) * 64u + (bid >> 3);    // XCD swizzle (512 % 8 == 0)
  u32 b  = id2 >> 8;
  u32 t  = (id2 >> 3) & 31;
  u32 r0 = (id2 & 7) * 4u;

  u32 tid = threadIdx.x;
  u32 lane = tid & 63, wave = tid >> 6;      // 4 waves, wave = cout quarter
  u32 l31 = lane & 31u, lh = lane >> 5;

  const u16* xb = xt + (size_t)b * 32u * P3 * 8u;
  u32 pBase = ((t + 1) * PD + (r0 + 1)) * PD + 1;

  // wave w stages kb=w: A 4x1KB (couts q*64..q*64+63), B 2x(2x512B) halves
#define STAGE(T_, BUF_) do {                                                  \
    u32 Tn_ = (u32)(T_);                                                      \
    u32 d_ = Tn_ >> 3, kg_ = (Tn_ & 7u) * 4u + wave;                          \
    const u16* gA_ = wb + (size_t)(d_ * 32u + kg_) * 2048u + lane * 8u;       \
    u16* dA_ = &ldsA[BUF_][wave][0][0];                                       \
    gload_lds16(gA_,           dA_);                                          \
    gload_lds16(gA_ + 512u,    dA_ + 512u);                                   \
    gload_lds16(gA_ + 1024u,   dA_ + 1024u);                                  \
    gload_lds16(gA_ + 1536u,   dA_ + 1536u);                                  \
    const u16* gB_ = xb + (size_t)kg_ * P3 * 8u                               \
        + (u32)((int)pBase + tapOff(d_)) * 8u                                 \
        + (lh * (u32)PD + l31) * 8u;                                          \
    u16* dB_ = &ldsB[BUF_][wave][0][0];                                       \
    gload_lds16(gB_,                  dB_);                                   \
    gload_lds16(gB_ + 2u * PD * 8u,   dB_ + 512u);                            \
  } while (0)

  // frag reads for one ks (K=16): 2 A + 4 B ds_read_b128; kb = ks*2 + lh
#define RD(AS, BS, KS) do {                                                   \
    u32 kb_ = (u32)(KS) * 2u + lh;                                            \
    AS[0] = *(const bf16x8*)&ldsA[buf][kb_][wave * 64 + l31][0];              \
    AS[1] = *(const bf16x8*)&ldsA[buf][kb_][wave * 64 + 32 + l31][0];         \
    _Pragma("unroll")                                                         \
    for (int nt = 0; nt < 4; ++nt)                                            \
      BS[nt] = *(const bf16x8*)&ldsB[buf][kb_][nt * 32 + l31][0];             \
  } while (0)

#define MF(A, Bv, C) __builtin_amdgcn_mfma_f32_32x32x16_bf16(A, Bv, C, 0, 0, 0)

#define MM(AS, BS) do {                                                       \
    __builtin_amdgcn_s_setprio(1);                                            \
    _Pragma("unroll")                                                         \
    for (int mt = 0; mt < 2; ++mt)                                            \
      _Pragma("unroll")                                                       \
      for (int nt = 0; nt < 4; ++nt)                                          \
        acc[mt][nt] = MF(AS[mt], BS[nt], acc[mt][nt]);                        \
    __builtin_amdgcn_s_setprio(0);                                            \
  } while (0)

  f32x16 acc[2][4];
#pragma unroll
  for (int i = 0; i < 2; ++i)
#pragma unroll
    for (int j = 0; j < 4; ++j) acc[i][j] = (f32x16)0.0f;

  bf16x8 aX[2], bX[4], aY[2], bY[4];

  STAGE(0, 0);
  __syncthreads();                 // drains vmcnt(0): buf0 ready

#pragma unroll 1
  for (int T = 0; T < 56; ++T) {
    const u32 buf = (u32)T & 1u;
    if (T + 1 < 56) STAGE(T + 1, buf ^ 1u);  // issue-first: full step to land
    RD(aX, bX, 0);
    RD(aY, bY, 1);
    MM(aX, bX);                    // ks0 (ks1 reads drain underneath)
    MM(aY, bY);                    // ks1
    if (T + 1 < 56) __syncthreads();
  }

#undef MM
#undef MF
#undef RD
#undef STAGE

  // epilogue: 32x32 C/D: col = lane&31 (spatial), row = (reg&3)+8*(reg>>2)
  //           +4*lh (cout within 32)   (verified R4/R9)
  u32 rbase = lh * 4u;
  float* ob = out + (size_t)(b * COUT + wave * 64u) * SPAT
                  + t * 1024u + r0 * 32u;
#pragma unroll
  for (int mt = 0; mt < 2; ++mt)
#pragma unroll
    for (int nt = 0; nt < 4; ++nt) {
      f32x16 v = acc[mt][nt];
#pragma unroll
      for (int reg = 0; reg < 16; ++reg) {
        u32 row = (u32)(reg & 3) + 8u * (u32)(reg >> 2) + rbase;
        ob[(size_t)(mt * 32u + row) * SPAT + nt * 32u + l31] = v[reg];
      }
    }
}

extern "C" void kernel_launch(void* const* d_in, const int* in_sizes, int n_in,
                              void* d_out, int out_size, void* d_ws, size_t ws_size,
                              hipStream_t stream) {
  const float* x = (const float*)d_in[0];
  const float* W = (const float*)d_in[1];
  float* out = (float*)d_out;
  u16* xt  = (u16*)d_ws;
  u16* wbf = (u16*)((char*)d_ws + WB_OFF_BYTES);

  u32 zThreads = 64u * (u32)P3;
  hipLaunchKernelGGL(zero_border,   dim3((zThreads + 255) / 256), dim3(256), 0, stream, xt);
  hipLaunchKernelGGL(convert_w,     dim3(224),  dim3(256), 0, stream, W, wbf);
  hipLaunchKernelGGL(transpose_pad, dim3(1024), dim3(256), 0, stream, x, xt);
  hipLaunchKernelGGL(conv_main,     dim3(512),  dim3(256), 0, stream, xt, wbf, out);
}

// Round 13
// 95.101 us; speedup vs baseline: 1.0693x; 1.0693x over previous
//
#include <hip/hip_runtime.h>

typedef unsigned int u32;
typedef unsigned short u16;

#define B_   2
#define CIN  256
#define COUT 256
#define PD   34
#define PLANE (PD*PD)        // 1156
#define P3   (PD*PD*PD)      // 39304
#define SPAT 32768           // 32*32*32

// xt2: [b][kg(32)][p(P3)][8]  (granule = 8 cin = 16B)
#define XT_BYTES ((size_t)B_ * 32 * P3 * 8 * 2)
#define WB_OFF_BYTES XT_BYTES

typedef __attribute__((ext_vector_type(8)))  short bf16x8;
typedef __attribute__((ext_vector_type(8)))  u16   u16x8;
typedef __attribute__((ext_vector_type(16))) float f32x16;

__device__ __forceinline__ u16 f2bf(float f) {
  union { float f; u32 u; } v; v.f = f;
  u32 r = v.u + 0x7FFFu + ((v.u >> 16) & 1u);   // RNE
  return (u16)(r >> 16);
}

__device__ __forceinline__ void gload_lds16(const void* g, void* l) {
  __builtin_amdgcn_global_load_lds(
      (const __attribute__((address_space(1))) u32*)g,
      (__attribute__((address_space(3))) u32*)l,
      16, 0, 0);
}

__device__ __forceinline__ int tapOff(u32 d) {
  return (d == 1) ? -PLANE : (d == 2) ? PLANE
       : (d == 3) ? -PD    : (d == 4) ? PD
       : (d == 5) ? -1     : (d == 6) ? 1 : 0;
}

// ---------------- zero only the pad border of xt2 ---------------------------
__global__ void zero_border(u16* __restrict__ xt) {
  u32 idx = blockIdx.x * 256u + threadIdx.x;   // 64 * P3 granules
  if (idx >= 64u * (u32)P3) return;
  u32 bk = idx & 63u;                          // b*32 + kg
  u32 p  = idx >> 6;
  u32 t = p / PLANE, rem = p - t * PLANE, r = rem / PD, c = rem - r * PD;
  if (!((t == 0) | (t == 33) | (r == 0) | (r == 33) | (c == 0) | (c == 33)))
    return;
  *(u16x8*)(xt + ((size_t)bk * P3 + p) * 8) = (u16x8)0;
}

// ---------------- W fp32 -> bf16, wb2[d][kg][o][8] ---------------------------
__global__ void convert_w(const float* __restrict__ W, u16* __restrict__ wb) {
  u32 idx = blockIdx.x * 256u + threadIdx.x;   // 7*32*256 = 57344
  u32 o = idx & 255u, kgd = idx >> 8;          // kgd = d*32 + kg
  u32 kg = kgd & 31u, d = kgd >> 5;
  const float* src = W + (size_t)(d * 256u + o) * CIN + kg * 8u;
  float4 f0 = ((const float4*)src)[0];
  float4 f1 = ((const float4*)src)[1];
  u16x8 v;
  v[0] = f2bf(f0.x); v[1] = f2bf(f0.y); v[2] = f2bf(f0.z); v[3] = f2bf(f0.w);
  v[4] = f2bf(f1.x); v[5] = f2bf(f1.y); v[6] = f2bf(f1.z); v[7] = f2bf(f1.w);
  *(u16x8*)(wb + (size_t)idx * 8) = v;
}

// ------- x (b,i,t,r,c) fp32 -> xt2[b][kg][p][8], COALESCED ------------------
__global__ void transpose_pad(const float* __restrict__ x, u16* __restrict__ xt) {
  u32 wg = blockIdx.x;                 // 1024 = b(2) x t(32) x rq(4) x ih(4)
  u32 ih = wg & 3u, rq = (wg >> 2) & 3u, t = (wg >> 4) & 31u, b = wg >> 9;
  u32 tid = threadIdx.x;
  u32 r = tid >> 5, c = tid & 31u, rr = rq * 8u + r;
  u32 sOff = t * 1024u + rr * 32u + c;
  u32 p = ((t + 1) * PD + (rr + 1)) * PD + 1 + c;
#pragma unroll 1
  for (u32 g = 0; g < 8; ++g) {
    u32 ig = ih * 8u + g;
    u16x8 v;
#pragma unroll
    for (int j = 0; j < 8; ++j)
      v[j] = f2bf(x[(size_t)(b * 256u + ig * 8u + (u32)j) * SPAT + sOff]);
    *(u16x8*)(xt + ((size_t)(b * 32u + ig) * P3 + p) * 8) = v;
  }
}

// ---------------- main: 8-wave 256x256 tile, A in REGISTERS, B in LDS -------
// Wave grid 4(m)x2(n), wave-tile 64 cout x 128 spatial, 32x32x16 MFMA.
// 28 K-tiles of BK=64. A-frags (8/wave/tile) loaded global->VGPR one tile
// ahead (L2-hot W, no cross-wave dep -> no barrier needed for A). B staged
// to 64 KiB dbuf LDS (4 gload_lds/wave/tile). One s_barrier per tile with
// counted vmcnt(8) (only next tile's A-loads outstanding). LDS reads drop
// to 16/wave/tile (B only).
__global__ __launch_bounds__(512, 2)
void conv_main(const u16* __restrict__ xt, const u16* __restrict__ wb,
               float* __restrict__ out) {
  __shared__ __align__(16) u16 ldsB[2][8][256][8];   // 64 KiB

  u32 bid = blockIdx.x;
  u32 id2 = (bid & 7) * 32u + (bid >> 3);    // XCD swizzle (256 % 8 == 0)
  u32 b  = id2 >> 7;
  u32 t  = (id2 >> 2) & 31;
  u32 r0 = (id2 & 3) * 8u;

  u32 tid = threadIdx.x;
  u32 lane = tid & 63, wave = tid >> 6;
  u32 wm = wave >> 1, wn = wave & 1;         // 4(m) x 2(n) wave grid
  u32 l31 = lane & 31u, lh = lane >> 5;

  const u16* xb = xt + (size_t)b * 32u * P3 * 8u;
  u32 pBase = ((t + 1) * PD + (r0 + 1)) * PD + 1;

  u32 aBase = (lh * 256u + wm * 64u + l31) * 8u;   // u16 units
  u32 bLane = (lh * (u32)PD + l31) * 8u;

  // A frag (ks,mt): lane: cout = wm*64+mt*32+l31, kg = (T&3)*8 + ks*2 + lh
#define LOADA(DST, T_) do {                                                   \
    u32 Tn_ = (u32)(T_);                                                      \
    const u16* gA_ = wb + (size_t)((Tn_ >> 2) * 65536u + (Tn_ & 3u) * 16384u) \
                        + aBase;                                              \
    _Pragma("unroll")                                                         \
    for (int ks = 0; ks < 4; ++ks)                                            \
      _Pragma("unroll")                                                       \
      for (int mt = 0; mt < 2; ++mt)                                          \
        DST[ks][mt] = *(const bf16x8*)(gA_ + ks * 4096 + mt * 256);           \
  } while (0)

  // B stage: wave stages kb=wave; gload j covers n = j*64+lane
#define STAGEB(T_, BUF_) do {                                                 \
    u32 Tn_ = (u32)(T_);                                                      \
    u32 d_ = Tn_ >> 2, kg_ = (Tn_ & 3u) * 8u + wave;                          \
    const u16* gB_ = xb + (size_t)kg_ * (P3 * 8u)                             \
                        + (u32)((int)pBase + tapOff(d_)) * 8u + bLane;        \
    u16* dB_ = &ldsB[BUF_][wave][0][0];                                       \
    gload_lds16(gB_,                   dB_);                                  \
    gload_lds16(gB_ + 2u * PD * 8u,    dB_ + 512u);                           \
    gload_lds16(gB_ + 4u * PD * 8u,    dB_ + 1024u);                          \
    gload_lds16(gB_ + 6u * PD * 8u,    dB_ + 1536u);                          \
  } while (0)

  // B frag (ks,nt): n = wn*128 + nt*32 + l31, kb = ks*2 + lh
#define RDB(BS, BUF, KS) do {                                                 \
    u32 kb_ = (u32)(KS) * 2u + lh;                                            \
    _Pragma("unroll")                                                         \
    for (int nt = 0; nt < 4; ++nt)                                            \
      BS[nt] = *(const bf16x8*)&ldsB[BUF][kb_][wn * 128 + nt * 32 + l31][0];  \
  } while (0)

#define MF(A, Bv, C) __builtin_amdgcn_mfma_f32_32x32x16_bf16(A, Bv, C, 0, 0, 0)

#define MM(AR, KS, BS) do {                                                   \
    __builtin_amdgcn_s_setprio(1);                                            \
    _Pragma("unroll")                                                         \
    for (int mt = 0; mt < 2; ++mt)                                            \
      _Pragma("unroll")                                                       \
      for (int nt = 0; nt < 4; ++nt)                                          \
        acc[mt][nt] = MF(AR[KS][mt], BS[nt], acc[mt][nt]);                    \
    __builtin_amdgcn_s_setprio(0);                                            \
  } while (0)

#define COMPUTE(BUF, AR) do {                                                 \
    bf16x8 bX[4], bY[4];                                                      \
    RDB(bX, BUF, 0);                                                          \
    RDB(bY, BUF, 1);                                                          \
    MM(AR, 0, bX);                                                            \
    RDB(bX, BUF, 2);                                                          \
    MM(AR, 1, bY);                                                            \
    RDB(bY, BUF, 3);                                                          \
    MM(AR, 2, bX);                                                            \
    MM(AR, 3, bY);                                                            \
  } while (0)

#define TILE_BARRIER() do {                                                   \
    __builtin_amdgcn_sched_barrier(0);                                        \
    asm volatile("s_waitcnt vmcnt(8)" ::: "memory");                          \
    __builtin_amdgcn_s_barrier();                                             \
    __builtin_amdgcn_sched_barrier(0);                                        \
  } while (0)

  f32x16 acc[2][4];
#pragma unroll
  for (int i = 0; i < 2; ++i)
#pragma unroll
    for (int j = 0; j < 4; ++j) acc[i][j] = (f32x16)0.0f;

  bf16x8 aE[4][2], aO[4][2];

  // prologue: B(0) staged, A(0) loaded
  STAGEB(0, 0);
  LOADA(aE, 0);
  __builtin_amdgcn_sched_barrier(0);
  asm volatile("s_waitcnt vmcnt(0)" ::: "memory");
  __builtin_amdgcn_s_barrier();
  __builtin_amdgcn_sched_barrier(0);

#pragma unroll 1
  for (int T2 = 0; T2 < 14; ++T2) {
    int T = T2 * 2;
    // even tile T: buf0, aE; prefetch T+1 (B->buf1, A->aO)
    STAGEB(T + 1, 1);
    LOADA(aO, T + 1);
    COMPUTE(0, aE);
    TILE_BARRIER();
    // odd tile T+1: buf1, aO; prefetch T+2 (B->buf0, A->aE)
    if (T2 < 13) {
      STAGEB(T + 2, 0);
      LOADA(aE, T + 2);
    }
    COMPUTE(1, aO);
    if (T2 < 13) TILE_BARRIER();
  }

#undef TILE_BARRIER
#undef COMPUTE
#undef MM
#undef MF
#undef RDB
#undef STAGEB
#undef LOADA

  // epilogue: 32x32 C/D: col = lane&31 (spatial), row = (reg&3)+8*(reg>>2)
  //           +4*lh (cout within 32)   (verified R4/R9)
  u32 rbase = lh * 4u;
  float* ob = out + (size_t)(b * COUT + wm * 64u) * SPAT
                  + t * 1024u + r0 * 32u;
#pragma unroll
  for (int mt = 0; mt < 2; ++mt)
#pragma unroll
    for (int nt = 0; nt < 4; ++nt) {
      f32x16 v = acc[mt][nt];
#pragma unroll
      for (int reg = 0; reg < 16; ++reg) {
        u32 row = (u32)(reg & 3) + 8u * (u32)(reg >> 2) + rbase;
        ob[(size_t)(mt * 32u + row) * SPAT + wn * 128u + nt * 32u + l31] = v[reg];
      }
    }
}

extern "C" void kernel_launch(void* const* d_in, const int* in_sizes, int n_in,
                              void* d_out, int out_size, void* d_ws, size_t ws_size,
                              hipStream_t stream) {
  const float* x = (const float*)d_in[0];
  const float* W = (const float*)d_in[1];
  float* out = (float*)d_out;
  u16* xt  = (u16*)d_ws;
  u16* wbf = (u16*)((char*)d_ws + WB_OFF_BYTES);

  u32 zThreads = 64u * (u32)P3;
  hipLaunchKernelGGL(zero_border,   dim3((zThreads + 255) / 256), dim3(256), 0, stream, xt);
  hipLaunchKernelGGL(convert_w,     dim3(224),  dim3(256), 0, stream, W, wbf);
  hipLaunchKernelGGL(transpose_pad, dim3(1024), dim3(256), 0, stream, x, xt);
  hipLaunchKernelGGL(conv_main,     dim3(256),  dim3(512), 0, stream, xt, wbf, out);
}

// Round 14
// 92.183 us; speedup vs baseline: 1.1031x; 1.0317x over previous
//
#include <hip/hip_runtime.h>

typedef unsigned int u32;
typedef unsigned short u16;

#define B_   2
#define CIN  256
#define COUT 256
#define PD   34
#define PLANE (PD*PD)        // 1156
#define P3   (PD*PD*PD)      // 39304
#define SPAT 32768           // 32*32*32

// xt2: [b][kg(32)][p(P3)][8]  (granule = 8 cin = 16B)
#define XT_BYTES ((size_t)B_ * 32 * P3 * 8 * 2)
#define WB_OFF_BYTES XT_BYTES

typedef __attribute__((ext_vector_type(8)))  short bf16x8;
typedef __attribute__((ext_vector_type(8)))  u16   u16x8;
typedef __attribute__((ext_vector_type(16))) float f32x16;

__device__ __forceinline__ u16 f2bf(float f) {
  union { float f; u32 u; } v; v.f = f;
  u32 r = v.u + 0x7FFFu + ((v.u >> 16) & 1u);   // RNE
  return (u16)(r >> 16);
}

__device__ __forceinline__ void gload_lds16(const void* g, void* l) {
  __builtin_amdgcn_global_load_lds(
      (const __attribute__((address_space(1))) u32*)g,
      (__attribute__((address_space(3))) u32*)l,
      16, 0, 0);
}

__device__ __forceinline__ int tapOff(u32 d) {
  return (d == 1) ? -PLANE : (d == 2) ? PLANE
       : (d == 3) ? -PD    : (d == 4) ? PD
       : (d == 5) ? -1     : (d == 6) ? 1 : 0;
}

// ---------------- zero only the pad border of xt2 ---------------------------
__global__ void zero_border(u16* __restrict__ xt) {
  u32 idx = blockIdx.x * 256u + threadIdx.x;   // 64 * P3 granules
  if (idx >= 64u * (u32)P3) return;
  u32 bk = idx & 63u;                          // b*32 + kg
  u32 p  = idx >> 6;
  u32 t = p / PLANE, rem = p - t * PLANE, r = rem / PD, c = rem - r * PD;
  if (!((t == 0) | (t == 33) | (r == 0) | (r == 33) | (c == 0) | (c == 33)))
    return;
  *(u16x8*)(xt + ((size_t)bk * P3 + p) * 8) = (u16x8)0;
}

// ---------------- W fp32 -> bf16, wb2[d][kg][o][8] ---------------------------
__global__ void convert_w(const float* __restrict__ W, u16* __restrict__ wb) {
  u32 idx = blockIdx.x * 256u + threadIdx.x;   // 7*32*256 = 57344
  u32 o = idx & 255u, kgd = idx >> 8;          // kgd = d*32 + kg
  u32 kg = kgd & 31u, d = kgd >> 5;
  const float* src = W + (size_t)(d * 256u + o) * CIN + kg * 8u;
  float4 f0 = ((const float4*)src)[0];
  float4 f1 = ((const float4*)src)[1];
  u16x8 v;
  v[0] = f2bf(f0.x); v[1] = f2bf(f0.y); v[2] = f2bf(f0.z); v[3] = f2bf(f0.w);
  v[4] = f2bf(f1.x); v[5] = f2bf(f1.y); v[6] = f2bf(f1.z); v[7] = f2bf(f1.w);
  *(u16x8*)(wb + (size_t)idx * 8) = v;
}

// ------- x (b,i,t,r,c) fp32 -> xt2[b][kg][p][8], COALESCED ------------------
__global__ void transpose_pad(const float* __restrict__ x, u16* __restrict__ xt) {
  u32 wg = blockIdx.x;                 // 1024 = b(2) x t(32) x rq(4) x ih(4)
  u32 ih = wg & 3u, rq = (wg >> 2) & 3u, t = (wg >> 4) & 31u, b = wg >> 9;
  u32 tid = threadIdx.x;
  u32 r = tid >> 5, c = tid & 31u, rr = rq * 8u + r;
  u32 sOff = t * 1024u + rr * 32u + c;
  u32 p = ((t + 1) * PD + (rr + 1)) * PD + 1 + c;
#pragma unroll 1
  for (u32 g = 0; g < 8; ++g) {
    u32 ig = ih * 8u + g;
    u16x8 v;
#pragma unroll
    for (int j = 0; j < 8; ++j)
      v[j] = f2bf(x[(size_t)(b * 256u + ig * 8u + (u32)j) * SPAT + sOff]);
    *(u16x8*)(xt + ((size_t)(b * 32u + ig) * P3 + p) * 8) = v;
  }
}

// ---------------- main: 16-wave 256x256 tile, 32x32x16, dbuf BK=64 ----------
// R9 schedule, but 1024 threads = 16 waves = 4 waves/SIMD (2x latency hiding;
// m114 overlap WITHIN the block). Wave grid 4(m)x4(n), wave-tile 64x64.
// Per wave per tile: 4 gload_lds (stage role kb=w&7, H=w>>3), 16 ds_read_b128,
// 16 MFMA 32x32x16, one __syncthreads.
__global__ __launch_bounds__(1024, 4)
void conv_main(const u16* __restrict__ xt, const u16* __restrict__ wb,
               float* __restrict__ out) {
  // [buf][A=0/B=1][kb(8)][row'(256)][8]  = 128 KiB
  __shared__ __align__(16) u16 lds[2][2][8][256][8];

  u32 bid = blockIdx.x;
  u32 id2 = (bid & 7) * 32u + (bid >> 3);    // XCD swizzle (256 % 8 == 0)
  u32 b  = id2 >> 7;
  u32 t  = (id2 >> 2) & 31;
  u32 r0 = (id2 & 3) * 8u;

  u32 tid = threadIdx.x;
  u32 lane = tid & 63, wave = tid >> 6;      // 16 waves
  u32 wm = wave >> 2, wn = wave & 3;         // 4(m) x 4(n) wave grid
  u32 l31 = lane & 31u, lh = lane >> 5;
  u32 kbw = wave & 7u, Hw = wave >> 3;       // staging role

  const u16* xb = xt + (size_t)b * 32u * P3 * 8u;
  u32 pBase = ((t + 1) * PD + (r0 + 1)) * PD + 1;

  u32 aLane = lane * 8u;                                   // u16 units
  u32 bLane = (2u * lh * (u32)PD + l31) * 8u;

  // wave (kbw,Hw) stages its kb-region half (verified R7/R9 maps):
  // A rows' Hw*128 + c*64 + l  <->  cout (2c+Hw)*64 + l  (c: +1024 u16 src)
  // B rows' Hw*128 + c*64 + l  <->  n = (2c+(l>>5))*64 + Hw*32 + (l&31)
#define STAGE(KN) do {                                                        \
    u32 kn_ = (u32)(KN), buf_ = kn_ & 1u;                                     \
    u32 d_ = kn_ >> 2, kg_ = (kn_ & 3u) * 8u + kbw;                           \
    const u16* gA_ = wb + ((size_t)(d_ * 32u + kg_) * 256u + Hw * 64u) * 8u   \
                        + aLane;                                              \
    u16* dA_ = &lds[buf_][0][kbw][Hw * 128u][0];                              \
    gload_lds16(gA_,          dA_);                                           \
    gload_lds16(gA_ + 1024u,  dA_ + 512u);                                    \
    const u16* gB_ = xb + ((size_t)kg_ * P3                                   \
                          + (u32)((int)pBase + tapOff(d_))                    \
                          + Hw * (u32)PD) * 8u + bLane;                       \
    u16* dB_ = &lds[buf_][1][kbw][Hw * 128u][0];                              \
    gload_lds16(gB_,                    dB_);                                 \
    gload_lds16(gB_ + (u32)(4 * PD * 8), dB_ + 512u);                         \
  } while (0)

  // frag reads for one ks (K=16): 2 A + 2 B ds_read_b128; kb = ks*2 + lh
  // A row' = (wm&1)*128 + (wm>>1)*64 + mt*32 + l31
  // B row' = nt*128 + (wn>>1)*64 + (wn&1)*32 + l31
  u32 aRow = (wm & 1u) * 128u + (wm >> 1) * 64u + l31;
  u32 bRow = (wn >> 1) * 64u + (wn & 1u) * 32u + l31;

#define RD(AS, BS, KS) do {                                                   \
    u32 kb_ = (u32)(KS) * 2u + lh;                                            \
    AS[0] = *(const bf16x8*)&lds[buf][0][kb_][aRow][0];                       \
    AS[1] = *(const bf16x8*)&lds[buf][0][kb_][aRow + 32][0];                  \
    BS[0] = *(const bf16x8*)&lds[buf][1][kb_][bRow][0];                       \
    BS[1] = *(const bf16x8*)&lds[buf][1][kb_][bRow + 128][0];                 \
  } while (0)

#define MF(A, Bv, C) __builtin_amdgcn_mfma_f32_32x32x16_bf16(A, Bv, C, 0, 0, 0)

#define MM(AS, BS) do {                                                       \
    __builtin_amdgcn_s_setprio(1);                                            \
    _Pragma("unroll")                                                         \
    for (int mt = 0; mt < 2; ++mt)                                            \
      _Pragma("unroll")                                                       \
      for (int nt = 0; nt < 2; ++nt)                                          \
        acc[mt][nt] = MF(AS[mt], BS[nt], acc[mt][nt]);                        \
    __builtin_amdgcn_s_setprio(0);                                            \
  } while (0)

  f32x16 acc[2][2];
#pragma unroll
  for (int i = 0; i < 2; ++i)
#pragma unroll
    for (int j = 0; j < 2; ++j) acc[i][j] = (f32x16)0.0f;

  bf16x8 aX[2], bX[2], aY[2], bY[2];

  STAGE(0);
  __syncthreads();                 // drains vmcnt(0): buf0 ready

#pragma unroll 1
  for (int T = 0; T < 28; ++T) {
    const u32 buf = (u32)T & 1u;
    if (T + 1 < 28) STAGE(T + 1);  // issue-first: a full tile to land
    RD(aX, bX, 0);
    RD(aY, bY, 1);
    MM(aX, bX);                    // ks0 (ks1 reads drain underneath)
    RD(aX, bX, 2);
    MM(aY, bY);                    // ks1
    RD(aY, bY, 3);
    MM(aX, bX);                    // ks2
    MM(aY, bY);                    // ks3
    if (T + 1 < 28) __syncthreads();
  }

#undef MM
#undef MF
#undef RD
#undef STAGE

  // epilogue: 32x32 C/D: col = lane&31 (spatial), row = (reg&3)+8*(reg>>2)
  //           +4*lh (cout within 32)   (verified R4/R9)
  u32 rbase = lh * 4u;
  float* ob = out + (size_t)(b * COUT + wm * 64u) * SPAT
                  + t * 1024u + r0 * 32u;
#pragma unroll
  for (int mt = 0; mt < 2; ++mt)
#pragma unroll
    for (int nt = 0; nt < 2; ++nt) {
      f32x16 v = acc[mt][nt];
#pragma unroll
      for (int reg = 0; reg < 16; ++reg) {
        u32 row = (u32)(reg & 3) + 8u * (u32)(reg >> 2) + rbase;
        ob[(size_t)(mt * 32u + row) * SPAT + wn * 64u + nt * 32u + l31] = v[reg];
      }
    }
}

extern "C" void kernel_launch(void* const* d_in, const int* in_sizes, int n_in,
                              void* d_out, int out_size, void* d_ws, size_t ws_size,
                              hipStream_t stream) {
  const float* x = (const float*)d_in[0];
  const float* W = (const float*)d_in[1];
  float* out = (float*)d_out;
  u16* xt  = (u16*)d_ws;
  u16* wbf = (u16*)((char*)d_ws + WB_OFF_BYTES);

  u32 zThreads = 64u * (u32)P3;
  hipLaunchKernelGGL(zero_border,   dim3((zThreads + 255) / 256), dim3(256), 0, stream, xt);
  hipLaunchKernelGGL(convert_w,     dim3(224),  dim3(256), 0, stream, W, wbf);
  hipLaunchKernelGGL(transpose_pad, dim3(1024), dim3(256), 0, stream, x, xt);
  hipLaunchKernelGGL(conv_main,     dim3(256),  dim3(1024), 0, stream, xt, wbf, out);
}